// Round 10
// baseline (172.179 us; speedup 1.0000x reference)
//
#include <hip/hip_runtime.h>
#include <hip/hip_bf16.h>

#define N_NODES 50000
#define NE      800000
#define NT16    (NE / 16)
#define NTILES  (NE / 16)

typedef __attribute__((ext_vector_type(8)))  short bf16x8;
typedef __attribute__((ext_vector_type(4)))  float f32x4;
typedef __attribute__((ext_vector_type(4)))  int   i32x4;
typedef __attribute__((ext_vector_type(2)))  int   i32x2;

static __device__ __forceinline__ short f2bf(float x) {
    union { float f; unsigned u; } v; v.f = x;
    unsigned r = (v.u + 0x7fffu + ((v.u >> 16) & 1u)) >> 16;  // RNE
    return (short)r;
}
static __device__ __forceinline__ float bflo(unsigned u) {
    union { unsigned u; float f; } v; v.u = u << 16; return v.f;
}
static __device__ __forceinline__ float bfhi(unsigned u) {
    union { unsigned u; float f; } v; v.u = u & 0xffff0000u; return v.f;
}
static __device__ __forceinline__ unsigned pk2bf(float a, float b) {
    union { __hip_bfloat162 h; unsigned u; } v;
    float2 f; f.x = a; f.y = b;
    v.h = __float22bfloat162_rn(f);
    return v.u;
}

// ---- workspace image layout (bytes from image base) ----
// [W1f 32768][W2f 16384][b1c 256][b2c 128][gt1 512][gt2 256][w3 128] = 50432 B
#define OFF_W2   32768
#define OFF_B1   49152
#define OFF_B2   49408
#define OFF_GT1  49536
#define OFF_GT2  50048
#define OFF_W3   50304
#define IMG_B    50432
#define IMG_V4   (IMG_B / 16)   // 3152

// ---------------- fused prep: pack emb + weight images (16x16 frag order) + hist ----------------
// W1f frag id f = t*4+ks (t=0..7, ks=0..3): elem (lane,j):
//   W1[(ks*32 + (lane>>4)*8 + j)*128 + t*16 + (lane&15)]
// W2f frag id f = t2*4+ks (t2=0..3): W2[(ks*32+(lane>>4)*8+j)*64 + t2*16 + (lane&15)]
// gt1[f] (f<128), gt2[f], w3c[f] (f<64): feature-linear.

__global__ void prep_hist(const float* __restrict__ emb,
                          const int* __restrict__ src, const int* __restrict__ dst,
                          const float* __restrict__ W1, const float* __restrict__ b1,
                          const float* __restrict__ g1, const float* __restrict__ bt1,
                          const float* __restrict__ W2, const float* __restrict__ b2,
                          const float* __restrict__ g2, const float* __restrict__ bt2,
                          const float* __restrict__ W3,
                          ushort* __restrict__ embB, char* __restrict__ img,
                          int* __restrict__ outd, int* __restrict__ ind)
{
    const int i0 = blockIdx.x * 256 + threadIdx.x;
    const int n  = gridDim.x * 256;

    for (int t = i0; t < (N_NODES * 64 / 8); t += n) {
        const f32x4* p = (const f32x4*)(emb + (size_t)t * 8);
        f32x4 a = p[0], b = p[1];
        unsigned u0 = pk2bf(a[0], a[1]);
        unsigned u1 = pk2bf(a[2], a[3]);
        unsigned u2 = pk2bf(b[0], b[1]);
        unsigned u3 = pk2bf(b[2], b[3]);
        i32x4 o = {(int)u0, (int)u1, (int)u2, (int)u3};
        *(i32x4*)(embB + (size_t)t * 8) = o;
    }
    for (int t = i0; t < NE / 4; t += n) {
        i32x4 s4 = ((const i32x4*)src)[t];
        i32x4 d4 = ((const i32x4*)dst)[t];
        atomicAdd(outd + s4[0], 1); atomicAdd(outd + s4[1], 1);
        atomicAdd(outd + s4[2], 1); atomicAdd(outd + s4[3], 1);
        atomicAdd(ind + d4[0], 1); atomicAdd(ind + d4[1], 1);
        atomicAdd(ind + d4[2], 1); atomicAdd(ind + d4[3], 1);
    }
    ushort* W1f = (ushort*)img;
    for (int t = i0; t < 16384; t += n) {
        int j = t & 7, lane = (t >> 3) & 63, f = t >> 9;   // f = tt*4+ks
        int tt = f >> 2, ks = f & 3, g = lane >> 4, c = lane & 15;
        W1f[t] = f2bf(W1[(ks * 32 + g * 8 + j) * 128 + tt * 16 + c]);
    }
    ushort* W2f = (ushort*)(img + OFF_W2);
    for (int t = i0; t < 8192; t += n) {
        int j = t & 7, lane = (t >> 3) & 63, f = t >> 9;   // f = t2*4+ks
        int t2 = f >> 2, ks = f & 3, g = lane >> 4, c = lane & 15;
        W2f[t] = f2bf(W2[(ks * 32 + g * 8 + j) * 64 + t2 * 16 + c]);
    }
    if (i0 < 128) ((ushort*)(img + OFF_B1))[i0] = f2bf(b1[i0]);
    if (i0 < 64)  ((ushort*)(img + OFF_B2))[i0] = f2bf(b2[i0]);
    if (i0 < 128)
        ((unsigned*)(img + OFF_GT1))[i0] =
            (unsigned)(ushort)f2bf(g1[i0]) | ((unsigned)(ushort)f2bf(bt1[i0]) << 16);
    if (i0 < 64) {
        ((unsigned*)(img + OFF_GT2))[i0] =
            (unsigned)(ushort)f2bf(g2[i0]) | ((unsigned)(ushort)f2bf(bt2[i0]) << 16);
        ((ushort*)(img + OFF_W3))[i0] = f2bf(W3[i0]);
    }
}

// ---------------- main: 16x16x32 MFMA, transposed (features=M, edges=N) ----------------
// A (weights 16x32): lane l holds A[l&15][(l>>4)*8+j]
// B (data 32x16):    lane l holds B[(l>>4)*8+j][l&15]
// C: col=lane&15 (edge), row=(lane>>4)*4+reg (feature-local) [m89-verified]
// Per wave-tile: 16 edges. acc1=32, acc2=16, frags 16, pku 16 regs ->
// target total <=168 for 3 waves/SIMD. L1->L2 feature re-frag via 32
// ds_bpermute (no LDS staging; LDS stays 50.7KB -> 3 blocks/CU).

__global__ __launch_bounds__(256, 3) void edge_mlp16(
    const ushort* __restrict__ embB,
    const int*   __restrict__ src, const int* __restrict__ dst,
    const float* __restrict__ noise,
    const i32x4* __restrict__ WFimg,
    const float* __restrict__ b3p,
    const int* __restrict__ outd, const int* __restrict__ ind,
    float* __restrict__ out)
{
    __shared__ i32x4 ldsv[IMG_V4];
    char* ldsb = (char*)ldsv;

    const int tid = threadIdx.x;
    for (int i = tid; i < IMG_V4; i += 256) ldsv[i] = WFimg[i];
    __syncthreads();

    const int l = tid & 63;
    const int g = l >> 4;        // k-group 0..3
    const int c = l & 15;        // edge-in-tile / feature col

    const float b3v = b3p[0];

    bf16x8 bone = {};
    bone[0] = (g == 0) ? (short)0x3F80 : (short)0;   // B[k=0][e]=1

    // bpermute addresses (constant per lane)
    const int addrA = (((g & 1) * 2) * 16 + c) * 4;  // lane gs1*16+c
    const int addrB = addrA + 64;                    // lane (gs1+1)*16+c

    const int gw = blockIdx.x * 4 + (tid >> 6);
    const int nw = gridDim.x * 4;

    // ---- pipeline prologue: indices + all 4 fragments for first tile ----
    int sn, dn;
    bf16x8 fS0, fS1, fD0, fD1;
    {
        int t0 = (gw < NT16) ? gw : (NT16 - 1);
        int e0p = t0 * 16 + c;
        sn = src[e0p]; dn = dst[e0p];
        const ushort* sp = embB + (size_t)sn * 64;
        const ushort* dp = embB + (size_t)dn * 64;
        fS0 = *(const bf16x8*)(sp + g * 8);
        fS1 = *(const bf16x8*)(sp + 32 + g * 8);
        fD0 = *(const bf16x8*)(dp + g * 8);
        fD1 = *(const bf16x8*)(dp + 32 + g * 8);
    }

    for (int tile = gw; tile < NT16; tile += nw) {
        unsigned tz;
        asm volatile("v_mov_b32 %0, 0" : "=v"(tz));   // anti-LICM anchor (LDS)
        const char* ldz = ldsb + tz;

        const int e0 = tile * 16 + c;

        // ---- loop top: next indices + epilogue loads ----
        const int tn  = tile + nw;
        const int tcl = (tn < NT16) ? tn : tile;
        const int e0n = tcl * 16 + c;
        int snN = src[e0n];
        int dnN = dst[e0n];
        float nz = noise[e0];
        int odv = outd[sn];
        int idv = ind[dn];

        // ---- layer 1: 8 t x 4 ks MFMAs + 8 bias ----
        const ushort* W1z = (const ushort*)ldz;
        f32x4 acc1[8] = {};
#pragma unroll
        for (int ks = 0; ks < 4; ++ks) {
            bf16x8 bf = (ks == 0) ? fS0 : (ks == 1) ? fS1 : (ks == 2) ? fD0 : fD1;
#pragma unroll
            for (int t = 0; t < 8; ++t) {
                bf16x8 w = *(const bf16x8*)(W1z + (t * 4 + ks) * 512 + l * 8);
                acc1[t] = __builtin_amdgcn_mfma_f32_16x16x32_bf16(w, bf, acc1[t], 0, 0, 0);
            }
        }
        const ushort* b1z = (const ushort*)(ldz + OFF_B1);
#pragma unroll
        for (int t = 0; t < 8; ++t) {
            bf16x8 w = {};
            short bv = b1z[t * 16 + c];
            w[0] = (g == 0) ? bv : (short)0;
            acc1[t] = __builtin_amdgcn_mfma_f32_16x16x32_bf16(w, bone, acc1[t], 0, 0, 0);
        }

        // ---- LN1 stats: 32 vals/lane + xor16 + xor32 ----
        float s0 = 0.f, s1 = 0.f, q0 = 0.f, q1 = 0.f;
#pragma unroll
        for (int t = 0; t < 8; ++t) {
            float v0 = acc1[t][0], v1 = acc1[t][1], v2 = acc1[t][2], v3 = acc1[t][3];
            s0 += v0 + v2; q0 = fmaf(v0, v0, fmaf(v2, v2, q0));
            s1 += v1 + v3; q1 = fmaf(v1, v1, fmaf(v3, v3, q1));
        }
        float s = s0 + s1, q = q0 + q1;
        s += __shfl_xor(s, 16); s += __shfl_xor(s, 32);
        q += __shfl_xor(q, 16); q += __shfl_xor(q, 32);
        const float mu = s * (1.0f / 128.0f);
        const float rs = rsqrtf(q * (1.0f / 128.0f) - mu * mu + 1e-5f);
        const float c0 = -mu * rs;

        // ---- LN1 apply + relu + pack: pku[t][0..1] ----
        unsigned pku[8][2];
#pragma unroll
        for (int t = 0; t < 8; ++t) {
            i32x4 pg = *(const i32x4*)(ldz + OFF_GT1 + t * 64 + g * 16);
            float y0, y1, y2, y3;
            {
                float w0 = fmaf(acc1[t][0], rs, c0);
                y0 = fmaxf(fmaf(w0, bflo((unsigned)pg[0]), bfhi((unsigned)pg[0])), 0.f);
                float w1 = fmaf(acc1[t][1], rs, c0);
                y1 = fmaxf(fmaf(w1, bflo((unsigned)pg[1]), bfhi((unsigned)pg[1])), 0.f);
                float w2 = fmaf(acc1[t][2], rs, c0);
                y2 = fmaxf(fmaf(w2, bflo((unsigned)pg[2]), bfhi((unsigned)pg[2])), 0.f);
                float w3 = fmaf(acc1[t][3], rs, c0);
                y3 = fmaxf(fmaf(w3, bflo((unsigned)pg[3]), bfhi((unsigned)pg[3])), 0.f);
            }
            pku[t][0] = pk2bf(y0, y1);
            pku[t][1] = pk2bf(y2, y3);
        }

        // ---- layer 2: per ks, build B-frag via bpermute, 4 t2 MFMAs ----
        const ushort* W2z = (const ushort*)(ldz + OFF_W2);
        f32x4 acc2[4] = {};
#pragma unroll
        for (int ks = 0; ks < 4; ++ks) {
            // candidates t=2ks (g<2) vs t=2ks+1 (g>=2)
            int a0 = __builtin_amdgcn_ds_bpermute(addrA, (int)pku[2 * ks][0]);
            int b0 = __builtin_amdgcn_ds_bpermute(addrA, (int)pku[2 * ks + 1][0]);
            int a1 = __builtin_amdgcn_ds_bpermute(addrA, (int)pku[2 * ks][1]);
            int b1_ = __builtin_amdgcn_ds_bpermute(addrA, (int)pku[2 * ks + 1][1]);
            int a2 = __builtin_amdgcn_ds_bpermute(addrB, (int)pku[2 * ks][0]);
            int b2_ = __builtin_amdgcn_ds_bpermute(addrB, (int)pku[2 * ks + 1][0]);
            int a3 = __builtin_amdgcn_ds_bpermute(addrB, (int)pku[2 * ks][1]);
            int b3_ = __builtin_amdgcn_ds_bpermute(addrB, (int)pku[2 * ks + 1][1]);
            union { i32x4 i; bf16x8 b; } u;
            u.i[0] = (g & 2) ? b0 : a0;
            u.i[1] = (g & 2) ? b1_ : a1;
            u.i[2] = (g & 2) ? b2_ : a2;
            u.i[3] = (g & 2) ? b3_ : a3;
#pragma unroll
            for (int t2 = 0; t2 < 4; ++t2) {
                bf16x8 w = *(const bf16x8*)(W2z + (t2 * 4 + ks) * 512 + l * 8);
                acc2[t2] = __builtin_amdgcn_mfma_f32_16x16x32_bf16(w, u.b, acc2[t2], 0, 0, 0);
            }
        }
        const ushort* b2z = (const ushort*)(ldz + OFF_B2);
#pragma unroll
        for (int t2 = 0; t2 < 4; ++t2) {
            bf16x8 w = {};
            short bv = b2z[t2 * 16 + c];
            w[0] = (g == 0) ? bv : (short)0;
            acc2[t2] = __builtin_amdgcn_mfma_f32_16x16x32_bf16(w, bone, acc2[t2], 0, 0, 0);
        }

        // ---- prefetch ALL next-tile frags here (acc1/pku dead) ----
        {
            const ushort* spn = embB + (size_t)snN * 64;
            const ushort* dpn = embB + (size_t)dnN * 64;
            fS0 = *(const bf16x8*)(spn + g * 8);
            fS1 = *(const bf16x8*)(spn + 32 + g * 8);
            fD0 = *(const bf16x8*)(dpn + g * 8);
            fD1 = *(const bf16x8*)(dpn + 32 + g * 8);
        }

        // ---- LN2 stats: 16 vals/lane + xor16 + xor32 ----
        float t0 = 0.f, t1 = 0.f, p0 = 0.f, p1 = 0.f;
#pragma unroll
        for (int t2 = 0; t2 < 4; ++t2) {
            float v0 = acc2[t2][0], v1 = acc2[t2][1], v2 = acc2[t2][2], v3 = acc2[t2][3];
            t0 += v0 + v2; p0 = fmaf(v0, v0, fmaf(v2, v2, p0));
            t1 += v1 + v3; p1 = fmaf(v1, v1, fmaf(v3, v3, p1));
        }
        float s2 = t0 + t1, q2 = p0 + p1;
        s2 += __shfl_xor(s2, 16); s2 += __shfl_xor(s2, 32);
        q2 += __shfl_xor(q2, 16); q2 += __shfl_xor(q2, 32);
        const float mu2 = s2 * (1.0f / 64.0f);
        const float rs2 = rsqrtf(q2 * (1.0f / 64.0f) - mu2 * mu2 + 1e-5f);
        const float c02 = -mu2 * rs2;

        // ---- LN2 apply + relu + dot(W3) ----
        float lg = 0.f;
#pragma unroll
        for (int t2 = 0; t2 < 4; ++t2) {
            i32x4 pg = *(const i32x4*)(ldz + OFF_GT2 + t2 * 64 + g * 16);
            i32x2 wq = *(const i32x2*)(ldz + OFF_W3 + t2 * 32 + g * 8);
#pragma unroll
            for (int r = 0; r < 4; ++r) {
                unsigned ug = (unsigned)pg[r];
                unsigned wu = (unsigned)wq[r >> 1];
                float w3v = (r & 1) ? bfhi(wu) : bflo(wu);
                float w = fmaf(acc2[t2][r], rs2, c02);
                float y = fmaxf(fmaf(w, bflo(ug), bfhi(ug)), 0.f);
                lg = fmaf(y, w3v, lg);
            }
        }
        lg += __shfl_xor(lg, 16);
        lg += __shfl_xor(lg, 32);
        lg += b3v;

        // ---- gate + degree norm (g==0 lanes: 16 edges) ----
        if (g == 0) {
            float z = __logf(nz) - log1pf(-nz) + lg;
            float gate = 1.0f / (1.0f + __expf(-z));
            int od = odv; if (od < 1) od = 1;
            int idg = idv; if (idg < 1) idg = 1;
            out[e0] = gate * (rsqrtf((float)od) * rsqrtf((float)idg));
        }

        sn = snN; dn = dnN;
    }
}

// ================= R2 fallback (validated) — used if ws too small =================

__global__ void degree_hist(const int* __restrict__ src, const int* __restrict__ dst,
                            int* __restrict__ outd, int* __restrict__ ind) {
    int i = blockIdx.x * 256 + threadIdx.x;
    if (i < NE) {
        atomicAdd(outd + src[i], 1);
        atomicAdd(ind + dst[i], 1);
    }
}

__global__ __launch_bounds__(256, 2) void edge_mlp_mfma(
    const float* __restrict__ emb,
    const int*   __restrict__ src, const int* __restrict__ dst,
    const float* __restrict__ noise,
    const float* __restrict__ W1, const float* __restrict__ b1,
    const float* __restrict__ g1, const float* __restrict__ bt1,
    const float* __restrict__ W2, const float* __restrict__ b2,
    const float* __restrict__ g2, const float* __restrict__ bt2,
    const float* __restrict__ W3, const float* __restrict__ b3,
    const int*   __restrict__ outd, const int* __restrict__ ind,
    float* __restrict__ out)
{
    __shared__ short lds[32768];
    const int tid = threadIdx.x;
    const int wid = tid >> 6;
    const int l   = tid & 63;
    const int g   = l >> 4;
    const int c   = l & 15;

    for (int i = tid; i < 16384; i += 256) {
        int j = i & 7, lane = (i >> 3) & 63, p = i >> 9;
        int ks = p >> 3, t = p & 7;
        int row = ks * 32 + (lane >> 4) * 8 + j;
        int col = t * 16 + (lane & 15);
        lds[i] = f2bf(W1[row * 128 + col]);
    }
    for (int i = tid; i < 8192; i += 256) {
        int j = i & 7, lane = (i >> 3) & 63, p = i >> 9;
        int ks = p >> 2, t = p & 3;
        int row = ks * 32 + (lane >> 4) * 8 + j;
        int col = t * 16 + (lane & 15);
        lds[16384 + i] = f2bf(W2[row * 64 + col]);
    }
    __syncthreads();

    short* Hl = lds + 24576 + wid * 2048;
    float b1v[8], g1v[8], t1v[8];
#pragma unroll
    for (int t = 0; t < 8; ++t) { int f = t * 16 + c; b1v[t] = b1[f]; g1v[t] = g1[f]; t1v[t] = bt1[f]; }
    float b2v[4], g2v[4], t2v[4], w3v[4];
#pragma unroll
    for (int t = 0; t < 4; ++t) { int f = t * 16 + c; b2v[t] = b2[f]; g2v[t] = g2[f]; t2v[t] = bt2[f]; w3v[t] = W3[f]; }
    const float b3v = b3[0];

    const int gw = blockIdx.x * 4 + wid;
    const int nw = gridDim.x * 4;

    for (int tile = gw; tile < NTILES; tile += nw) {
        const int e0 = tile * 16 + c;
        const int sn = src[e0], dn = dst[e0];
        const f32x4* sp = (const f32x4*)(emb + (size_t)sn * 64);
        const f32x4* dp = (const f32x4*)(emb + (size_t)dn * 64);
        f32x4 u[8];
        u[0] = sp[2 * g]; u[1] = sp[2 * g + 1];
        u[2] = sp[8 + 2 * g]; u[3] = sp[8 + 2 * g + 1];
        u[4] = dp[2 * g]; u[5] = dp[2 * g + 1];
        u[6] = dp[8 + 2 * g]; u[7] = dp[8 + 2 * g + 1];

        bf16x8 a1[4];
#pragma unroll
        for (int ks = 0; ks < 4; ++ks) {
            f32x4 x0 = u[2 * ks], x1 = u[2 * ks + 1];
            bf16x8 a;
            a[0] = f2bf(x0[0]); a[1] = f2bf(x0[1]); a[2] = f2bf(x0[2]); a[3] = f2bf(x0[3]);
            a[4] = f2bf(x1[0]); a[5] = f2bf(x1[1]); a[6] = f2bf(x1[2]); a[7] = f2bf(x1[3]);
            a1[ks] = a;
        }
        f32x4 acc1[8];
#pragma unroll
        for (int t = 0; t < 8; ++t) { f32x4 z = {b1v[t], b1v[t], b1v[t], b1v[t]}; acc1[t] = z; }
#pragma unroll
        for (int ks = 0; ks < 4; ++ks) {
#pragma unroll
            for (int t = 0; t < 8; ++t) {
                bf16x8 b = *(const bf16x8*)(lds + (ks * 8 + t) * 512 + l * 8);
                acc1[t] = __builtin_amdgcn_mfma_f32_16x16x32_bf16(a1[ks], b, acc1[t], 0, 0, 0);
            }
        }
        float mean[4], rstd[4];
#pragma unroll
        for (int r = 0; r < 4; ++r) {
            float s = acc1[0][r];
#pragma unroll
            for (int t = 1; t < 8; ++t) s += acc1[t][r];
            s += __shfl_xor(s, 1); s += __shfl_xor(s, 2);
            s += __shfl_xor(s, 4); s += __shfl_xor(s, 8);
            float m = s * (1.0f / 128.0f);
            float q = 0.f;
#pragma unroll
            for (int t = 0; t < 8; ++t) { float d = acc1[t][r] - m; q = fmaf(d, d, q); }
            q += __shfl_xor(q, 1); q += __shfl_xor(q, 2);
            q += __shfl_xor(q, 4); q += __shfl_xor(q, 8);
            mean[r] = m; rstd[r] = rsqrtf(q * (1.0f / 128.0f) + 1e-5f);
        }
#pragma unroll
        for (int r = 0; r < 4; ++r) {
            int rw = g * 4 + r;
            int swz = (rw & 7) << 3;
#pragma unroll
            for (int t = 0; t < 8; ++t) {
                float y = fmaf((acc1[t][r] - mean[r]) * rstd[r], g1v[t], t1v[t]);
                y = fmaxf(y, 0.f);
                Hl[rw * 128 + ((t * 16 + c) ^ swz)] = f2bf(y);
            }
        }
        bf16x8 a2[4];
        const int swzr = (c & 7) << 3;
#pragma unroll
        for (int ks = 0; ks < 4; ++ks)
            a2[ks] = *(const bf16x8*)(Hl + c * 128 + ((ks * 32 + g * 8) ^ swzr));

        f32x4 acc2[4];
#pragma unroll
        for (int t = 0; t < 4; ++t) { f32x4 z = {b2v[t], b2v[t], b2v[t], b2v[t]}; acc2[t] = z; }
#pragma unroll
        for (int ks = 0; ks < 4; ++ks) {
#pragma unroll
            for (int t = 0; t < 4; ++t) {
                bf16x8 b = *(const bf16x8*)(lds + 16384 + (ks * 4 + t) * 512 + l * 8);
                acc2[t] = __builtin_amdgcn_mfma_f32_16x16x32_bf16(a2[ks], b, acc2[t], 0, 0, 0);
            }
        }
        float logit[4];
#pragma unroll
        for (int r = 0; r < 4; ++r) {
            float s = acc2[0][r] + acc2[1][r] + acc2[2][r] + acc2[3][r];
            s += __shfl_xor(s, 1); s += __shfl_xor(s, 2);
            s += __shfl_xor(s, 4); s += __shfl_xor(s, 8);
            float m = s * (1.0f / 64.0f);
            float q = 0.f;
#pragma unroll
            for (int t = 0; t < 4; ++t) { float d = acc2[t][r] - m; q = fmaf(d, d, q); }
            q += __shfl_xor(q, 1); q += __shfl_xor(q, 2);
            q += __shfl_xor(q, 4); q += __shfl_xor(q, 8);
            float rs = rsqrtf(q * (1.0f / 64.0f) + 1e-5f);
            float p = 0.f;
#pragma unroll
            for (int t = 0; t < 4; ++t) {
                float y = fmaf((acc2[t][r] - m) * rs, g2v[t], t2v[t]);
                y = fmaxf(y, 0.f);
                p = fmaf(y, w3v[t], p);
            }
            p += __shfl_xor(p, 1); p += __shfl_xor(p, 2);
            p += __shfl_xor(p, 4); p += __shfl_xor(p, 8);
            logit[r] = p + b3v;
        }
        if (c < 4) {
            int e = tile * 16 + g * 4 + c;
            float lg = (c == 0) ? logit[0] : (c == 1) ? logit[1] : (c == 2) ? logit[2] : logit[3];
            float nz = noise[e];
            float z = __logf(nz) - log1pf(-nz) + lg;
            float gate = 1.0f / (1.0f + __expf(-z));
            int od = outd[src[e]]; if (od < 1) od = 1;
            int idg = ind[dst[e]]; if (idg < 1) idg = 1;
            out[e] = gate * (rsqrtf((float)od) * rsqrtf((float)idg));
        }
    }
}

// ---------------- launch ----------------

extern "C" void kernel_launch(void* const* d_in, const int* in_sizes, int n_in,
                              void* d_out, int out_size, void* d_ws, size_t ws_size,
                              hipStream_t stream) {
    const float* emb   = (const float*)d_in[0];
    const int*   src   = (const int*)  d_in[1];
    const int*   dst   = (const int*)  d_in[2];
    const float* noise = (const float*)d_in[3];
    const float* W1  = (const float*)d_in[4];
    const float* b1  = (const float*)d_in[5];
    const float* g1  = (const float*)d_in[6];
    const float* bt1 = (const float*)d_in[7];
    const float* W2  = (const float*)d_in[8];
    const float* b2  = (const float*)d_in[9];
    const float* g2  = (const float*)d_in[10];
    const float* bt2 = (const float*)d_in[11];
    const float* W3  = (const float*)d_in[12];
    const float* b3  = (const float*)d_in[13];

    char* ws = (char*)d_ws;
    const size_t NEED = 6400000 + IMG_B + 400000;

    if (ws_size >= NEED) {
        ushort* embB = (ushort*)ws;                       // 6,400,000 B
        char*   img  = ws + 6400000;                      // 50,432 B
        int* outd = (int*)(ws + 6400000 + IMG_B);
        int* ind  = outd + N_NODES;

        hipMemsetAsync(outd, 0, 2 * N_NODES * sizeof(int), stream);
        prep_hist<<<2048, 256, 0, stream>>>(emb, src, dst, W1, b1, g1, bt1,
                                            W2, b2, g2, bt2, W3,
                                            embB, img, outd, ind);
        edge_mlp16<<<1536, 256, 0, stream>>>(embB, src, dst, noise, (const i32x4*)img,
                                             b3, outd, ind, (float*)d_out);
    } else {
        int* outd = (int*)ws;
        int* ind  = outd + N_NODES;
        hipMemsetAsync(outd, 0, 2 * N_NODES * sizeof(int), stream);
        degree_hist<<<(NE + 255) / 256, 256, 0, stream>>>(src, dst, outd, ind);
        edge_mlp_mfma<<<512, 256, 0, stream>>>(emb, src, dst, noise,
                                               W1, b1, g1, bt1,
                                               W2, b2, g2, bt2,
                                               W3, b3, outd, ind,
                                               (float*)d_out);
    }
}